// Round 2
// baseline (4562.829 us; speedup 1.0000x reference)
//
#include <hip/hip_runtime.h>
#include <hip/hip_fp16.h>

// LSTM: B=128, T=500 (499 steps used), in=265 (padded 288), H=512, out=123.
// Phase 1: prep kernels (new_x = tanh/onehot -> f16; weights -> f16; bias fold).
// Phase 2: persistent cooperative kernel. 8 batch-tiles (16 rows) x 32 h-col
//          slices (64 gate cols). Weight B-fragments live in REGISTERS
//          (wave = one gate, 64+36 VGPRs). Per-tile monotonic-counter barrier
//          (agent scope, bounded spin). btile = blockIdx&7 -> tile's 32 WGs
//          co-locate on one XCD under round-robin dispatch.
// Phase 3: output GEMM + sigmoid.

typedef _Float16 f16;
typedef _Float16 f16x8 __attribute__((ext_vector_type(8)));
typedef float f32x4 __attribute__((ext_vector_type(4)));

#define TS 499

// ---- ws layout (bytes) ----
#define NEWX_OFF   0ul
#define NEWX_BYTES (500ul*128*288*2)
#define HALL_OFF   (NEWX_OFF + NEWX_BYTES)
#define HALL_BYTES (500ul*128*512*2)
#define WHH_OFF    (HALL_OFF + HALL_BYTES)
#define WHH_BYTES  (2048ul*512*2)
#define WIH_OFF    (WHH_OFF + WHH_BYTES)
#define WIH_BYTES  (2048ul*288*2)
#define WFC_OFF    (WIH_OFF + WIH_BYTES)
#define WFC_BYTES  (128ul*512*2)
#define BIAS_OFF   (WFC_OFF + WFC_BYTES)
#define BIAS_BYTES (2048ul*4)
#define CNT_OFF    (BIAS_OFF + BIAS_BYTES)
#define CNT_BYTES  (1024ul)
#define WS_NEED    (CNT_OFF + CNT_BYTES)

__device__ __forceinline__ float tanh_dev(float x) {
    float ax = fabsf(x);
    float e  = __expf(-2.f * ax);
    float r  = (1.f - e) / (1.f + e);
    return copysignf(r, x);
}
__device__ __forceinline__ float sigm_dev(float x) {
    float e = __expf(-fabsf(x));
    float p = 1.f / (1.f + e);
    return x >= 0.f ? p : 1.f - p;
}

// ---------------- phase 1a: new_x = tanh(feats | onehot(diff) | onehot(ab)) ----------------
__global__ void __launch_bounds__(256) prep_newx(const float* __restrict__ x,
                                                 f16* __restrict__ newx) {
    const int t   = blockIdx.x;       // 0..498
    const int b0  = blockIdx.y * 16;
    const int tid = threadIdx.x;
    for (int bb = 0; bb < 16; ++bb) {
        const int b = b0 + bb;
        const float* xr = x + ((size_t)b * 500 + t) * 248;
        const int ab = (int)xr[246];
        const int df = (int)xr[247];
        f16* orow = newx + ((size_t)t * 128 + b) * 288;
        for (int k = tid; k < 288; k += 256) {
            float v;
            if (k < 246)      v = tanh_dev(xr[k]);
            else if (k < 257) v = (k - 246 == df) ? 0.76159415595576485f : 0.f;
            else if (k < 265) v = (k - 257 == ab) ? 0.76159415595576485f : 0.f;
            else              v = 0.f;
            orow[k] = (f16)v;
        }
    }
}

// ---------------- phase 1b: weights -> f16 (padded), bias combine ----------------
__global__ void __launch_bounds__(256) prep_w(const float* __restrict__ W_ih,
                                              const float* __restrict__ W_hh,
                                              const float* __restrict__ W_fc,
                                              const float* __restrict__ b_ih,
                                              const float* __restrict__ b_hh,
                                              f16* __restrict__ whh, f16* __restrict__ wih,
                                              f16* __restrict__ wfc, float* __restrict__ bias) {
    const int NHH = 2048 * 512;
    const int NIH = 2048 * 288;
    const int NFC = 128 * 512;
    const int NT  = NHH + NIH + NFC + 2048;
    for (int i = blockIdx.x * 256 + threadIdx.x; i < NT; i += gridDim.x * 256) {
        if (i < NHH) {
            whh[i] = (f16)W_hh[i];
        } else if (i < NHH + NIH) {
            int j2 = i - NHH; int rr = j2 / 288, kk = j2 % 288;
            wih[j2] = (kk < 265) ? (f16)W_ih[rr * 265 + kk] : (f16)0.f;
        } else if (i < NHH + NIH + NFC) {
            int j2 = i - (NHH + NIH); int rr = j2 >> 9, kk = j2 & 511;
            wfc[j2] = (rr < 123) ? (f16)W_fc[rr * 512 + kk] : (f16)0.f;
        } else {
            int j2 = i - (NHH + NIH + NFC);
            bias[j2] = b_ih[j2] + b_hh[j2];
        }
    }
}

// ---------------- phase 2: persistent sequential LSTM ----------------
__global__ void __launch_bounds__(256, 1) lstm_seq(const f16* __restrict__ newx,
                                                   f16* __restrict__ hall,
                                                   const f16* __restrict__ whh,
                                                   const f16* __restrict__ wih,
                                                   const float* __restrict__ bias,
                                                   unsigned* __restrict__ cnt) {
    __shared__ float gf[1024];
    const int tid   = threadIdx.x;
    const int btile = blockIdx.x & 7;   // tile's 32 WGs share blockIdx%8 -> same XCD
    const int hs    = blockIdx.x >> 3;

    // mfma identity: wave wg = gate wg; lane's B row / D col = hs*16 + (wl&15)
    const int wg = tid >> 6, wl = tid & 63;
    const int arow = wl & 15, kgrp = wl >> 4;
    const int grow = wg * 512 + hs * 16 + arow;

    // B fragments resident in registers
    f16x8 wh[16], wi[9];
    #pragma unroll
    for (int kc = 0; kc < 16; ++kc)
        wh[kc] = *(const f16x8*)(whh + (size_t)grow * 512 + kc * 32 + kgrp * 8);
    #pragma unroll
    for (int kc = 0; kc < 9; ++kc)
        wi[kc] = *(const f16x8*)(wih + (size_t)grow * 288 + kc * 32 + kgrp * 8);
    const float bb = bias[grow];   // D col = lane&15 -> same index as B row

    // elementwise identity: thread owns (batch row irow, h col jcol)
    const int l = tid >> 2, r = tid & 3;
    const int jcol = l & 15, irow = ((l >> 4) << 2) + r;
    float c_st = 0.f;

    const int abase = btile * 16 + arow;
    unsigned* const mycnt = cnt + btile * 32;   // 128B-strided per-tile counters

    // x A-fragment double buffer (statically indexed)
    f16x8 xa[9], xb[9];
    {
        const f16* q = newx + (size_t)abase * 288 + kgrp * 8;
        #pragma unroll
        for (int kc = 0; kc < 9; ++kc) xa[kc] = *(const f16x8*)(q + kc * 32);
    }

    auto step = [&](int t, f16x8 (&xu)[9], f16x8 (&xp)[9]) {
        f32x4 acc = {bb, bb, bb, bb};
        // x-projection part (independent of barrier)
        #pragma unroll
        for (int kc = 0; kc < 9; ++kc)
            acc = __builtin_amdgcn_mfma_f32_16x16x32_f16(xu[kc], wi[kc], acc, 0, 0, 0);
        // prefetch next step's x fragments (latency hides under spin + h phase)
        {
            const f16* q = newx + ((size_t)(t + 1) * 128 + abase) * 288 + kgrp * 8;
            #pragma unroll
            for (int kc = 0; kc < 9; ++kc) xp[kc] = *(const f16x8*)(q + kc * 32);
        }
        if (t > 0) {
            if (tid == 0) {
                const unsigned tgt = 32u * (unsigned)t;
                int spins = 0;
                while (__hip_atomic_load(mycnt, __ATOMIC_ACQUIRE,
                                         __HIP_MEMORY_SCOPE_AGENT) < tgt) {
                    __builtin_amdgcn_s_sleep(1);
                    if (++spins > (1 << 20)) break;   // deadlock-proof: degrade, don't hang
                }
            }
            __syncthreads();
            const f16* hp = hall + ((size_t)(t - 1) * 128 + abase) * 512 + kgrp * 8;
            #pragma unroll
            for (int kc = 0; kc < 16; ++kc)
                acc = __builtin_amdgcn_mfma_f32_16x16x32_f16(
                          *(const f16x8*)(hp + kc * 32), wh[kc], acc, 0, 0, 0);
        }
        // gate exchange: lane wl reg rr = gates[batch (wl>>4)*4+rr][col wl&15]
        *(f32x4*)(gf + tid * 4) = acc;
        __syncthreads();
        float iv = sigm_dev(gf[tid]);
        float fv = sigm_dev(gf[256 + tid]);
        float gv = tanh_dev(gf[512 + tid]);
        float ov = sigm_dev(gf[768 + tid]);
        c_st = fv * c_st + iv * gv;
        float hv = ov * tanh_dev(c_st);
        hall[((size_t)t * 128 + btile * 16 + irow) * 512 + hs * 16 + jcol] = (f16)hv;
        __syncthreads();   // all waves' h stores complete (vmcnt drained) before release
        if (tid == 0)
            __hip_atomic_fetch_add(mycnt, 1u, __ATOMIC_RELEASE, __HIP_MEMORY_SCOPE_AGENT);
    };

    for (int t = 0; t < TS; t += 2) {
        step(t, xa, xb);
        if (t + 1 < TS) step(t + 1, xb, xa);
    }
}

// ---------------- phase 3: out = sigmoid(h_all @ W_fc^T + b_fc) ----------------
__global__ void __launch_bounds__(256) out_gemm(const f16* __restrict__ hall,
                                                const f16* __restrict__ wfc,
                                                const float* __restrict__ bfc,
                                                float* __restrict__ out) {
    const int tid = threadIdx.x;
    const int w = tid >> 6, wl = tid & 63;
    const int arow = wl & 15, kgrp = wl >> 4;
    const long m0 = (long)blockIdx.x * 64 + w * 16;
    const f16* ap = hall + (m0 + arow) * 512 + kgrp * 8;
    f16x8 a[16];
    #pragma unroll
    for (int kc = 0; kc < 16; ++kc) a[kc] = *(const f16x8*)(ap + kc * 32);
    #pragma unroll
    for (int jt = 0; jt < 8; ++jt) {
        f32x4 acc = {0.f, 0.f, 0.f, 0.f};
        const f16* bp = wfc + (size_t)(jt * 16 + arow) * 512 + kgrp * 8;
        #pragma unroll
        for (int kc = 0; kc < 16; ++kc)
            acc = __builtin_amdgcn_mfma_f32_16x16x32_f16(a[kc], *(const f16x8*)(bp + kc * 32),
                                                         acc, 0, 0, 0);
        const int col = jt * 16 + arow;        // D col = lane&15
        if (col < 123) {
            const float bv = bfc[col];
            #pragma unroll
            for (int rr = 0; rr < 4; ++rr) {
                long m = m0 + kgrp * 4 + rr;   // D row = (lane>>4)*4 + reg
                int tt = (int)(m >> 7), b = (int)(m & 127);
                out[((size_t)b * 499 + tt) * 123 + col] = sigm_dev(acc[rr] + bv);
            }
        }
    }
}

extern "C" void kernel_launch(void* const* d_in, const int* in_sizes, int n_in,
                              void* d_out, int out_size, void* d_ws, size_t ws_size,
                              hipStream_t stream) {
    if (ws_size < WS_NEED) return;   // safe no-op: wrong answer, not a GPU hang

    const float* x    = (const float*)d_in[0];
    const float* W_ih = (const float*)d_in[1];
    const float* W_hh = (const float*)d_in[2];
    const float* b_ih = (const float*)d_in[3];
    const float* b_hh = (const float*)d_in[4];
    const float* W_fc = (const float*)d_in[5];
    const float* b_fc = (const float*)d_in[6];
    float* out = (float*)d_out;
    char* ws = (char*)d_ws;

    f16* newx   = (f16*)(ws + NEWX_OFF);
    f16* hall   = (f16*)(ws + HALL_OFF);
    f16* whh    = (f16*)(ws + WHH_OFF);
    f16* wih    = (f16*)(ws + WIH_OFF);
    f16* wfc    = (f16*)(ws + WFC_OFF);
    float* bias = (float*)(ws + BIAS_OFF);
    unsigned* cnt = (unsigned*)(ws + CNT_OFF);

    // counters must be 0 at the start of every call (graph replays don't re-poison)
    hipMemsetAsync(cnt, 0, CNT_BYTES, stream);

    prep_newx<<<dim3(TS, 8), 256, 0, stream>>>(x, newx);
    prep_w<<<512, 256, 0, stream>>>(W_ih, W_hh, W_fc, b_ih, b_hh, whh, wih, wfc, bias);

    void* args[6] = {&newx, &hall, &whh, &wih, &bias, &cnt};
    hipLaunchCooperativeKernel((const void*)lstm_seq, dim3(256), dim3(256), args,
                               0, stream);

    out_gemm<<<998, 256, 0, stream>>>(hall, wfc, b_fc, out);
}

// Round 3
// 1933.996 us; speedup vs baseline: 2.3593x; 2.3593x over previous
//
#include <hip/hip_runtime.h>
#include <hip/hip_fp16.h>

// LSTM: B=128, T=500 (499 steps used), in=265 (padded 288), H=512, out=123.
// Phase 2 redesign vs R2: inter-WG h exchange goes through the Infinity Cache
// (sc0 sc1 loads/stores = bypass L1+L2, coherent device-wide) with RELAXED
// atomics for the per-tile counter barrier -- NO buffer_wbl2 / buffer_inv
// (the agent acquire/release fences were ~9us/step of L2 flush latency).

typedef _Float16 f16;
typedef _Float16 f16x8 __attribute__((ext_vector_type(8)));
typedef float f32x4 __attribute__((ext_vector_type(4)));

#define TS 499

// ---- ws layout (bytes) ----
#define NEWX_OFF   0ul
#define NEWX_BYTES (500ul*128*288*2)
#define HALL_OFF   (NEWX_OFF + NEWX_BYTES)
#define HALL_BYTES (500ul*128*512*2)
#define WHH_OFF    (HALL_OFF + HALL_BYTES)
#define WHH_BYTES  (2048ul*512*2)
#define WIH_OFF    (WHH_OFF + WHH_BYTES)
#define WIH_BYTES  (2048ul*288*2)
#define WFC_OFF    (WIH_OFF + WIH_BYTES)
#define WFC_BYTES  (128ul*512*2)
#define BIAS_OFF   (WFC_OFF + WFC_BYTES)
#define BIAS_BYTES (2048ul*4)
#define CNT_OFF    (BIAS_OFF + BIAS_BYTES)
#define CNT_BYTES  (1024ul)
#define WS_NEED    (CNT_OFF + CNT_BYTES)

__device__ __forceinline__ float tanh_dev(float x) {
    float ax = fabsf(x);
    float e  = __expf(-2.f * ax);
    float r  = (1.f - e) / (1.f + e);
    return copysignf(r, x);
}
__device__ __forceinline__ float sigm_dev(float x) {
    float e = __expf(-fabsf(x));
    float p = 1.f / (1.f + e);
    return x >= 0.f ? p : 1.f - p;
}

// ---------------- phase 1a: new_x = tanh(feats | onehot(diff) | onehot(ab)) ----------------
__global__ void __launch_bounds__(256) prep_newx(const float* __restrict__ x,
                                                 f16* __restrict__ newx) {
    const int t   = blockIdx.x;       // 0..498
    const int b0  = blockIdx.y * 16;
    const int tid = threadIdx.x;
    for (int bb = 0; bb < 16; ++bb) {
        const int b = b0 + bb;
        const float* xr = x + ((size_t)b * 500 + t) * 248;
        const int ab = (int)xr[246];
        const int df = (int)xr[247];
        f16* orow = newx + ((size_t)t * 128 + b) * 288;
        for (int k = tid; k < 288; k += 256) {
            float v;
            if (k < 246)      v = tanh_dev(xr[k]);
            else if (k < 257) v = (k - 246 == df) ? 0.76159415595576485f : 0.f;
            else if (k < 265) v = (k - 257 == ab) ? 0.76159415595576485f : 0.f;
            else              v = 0.f;
            orow[k] = (f16)v;
        }
    }
}

// ---------------- phase 1b: weights -> f16 (padded), bias combine ----------------
__global__ void __launch_bounds__(256) prep_w(const float* __restrict__ W_ih,
                                              const float* __restrict__ W_hh,
                                              const float* __restrict__ W_fc,
                                              const float* __restrict__ b_ih,
                                              const float* __restrict__ b_hh,
                                              f16* __restrict__ whh, f16* __restrict__ wih,
                                              f16* __restrict__ wfc, float* __restrict__ bias) {
    const int NHH = 2048 * 512;
    const int NIH = 2048 * 288;
    const int NFC = 128 * 512;
    const int NT  = NHH + NIH + NFC + 2048;
    for (int i = blockIdx.x * 256 + threadIdx.x; i < NT; i += gridDim.x * 256) {
        if (i < NHH) {
            whh[i] = (f16)W_hh[i];
        } else if (i < NHH + NIH) {
            int j2 = i - NHH; int rr = j2 / 288, kk = j2 % 288;
            wih[j2] = (kk < 265) ? (f16)W_ih[rr * 265 + kk] : (f16)0.f;
        } else if (i < NHH + NIH + NFC) {
            int j2 = i - (NHH + NIH); int rr = j2 >> 9, kk = j2 & 511;
            wfc[j2] = (rr < 123) ? (f16)W_fc[rr * 512 + kk] : (f16)0.f;
        } else {
            int j2 = i - (NHH + NIH + NFC);
            bias[j2] = b_ih[j2] + b_hh[j2];
        }
    }
}

// ---------------- phase 2: persistent sequential LSTM ----------------
// 8 batch-tiles (16 rows) x 32 h-col slices (64 gate cols). Weights in VGPRs.
// h exchange at LLC via sc0 sc1; relaxed-atomic monotonic counter per tile.
__global__ void __launch_bounds__(256, 1) lstm_seq(const f16* __restrict__ newx,
                                                   f16* __restrict__ hall,
                                                   const f16* __restrict__ whh,
                                                   const f16* __restrict__ wih,
                                                   const float* __restrict__ bias,
                                                   unsigned* __restrict__ cnt) {
    __shared__ float gf[1024];
    const int tid   = threadIdx.x;
    const int btile = blockIdx.x & 7;
    const int hs    = blockIdx.x >> 3;

    // mfma identity: wave wg = gate wg; lane's B row / D col = hs*16 + (wl&15)
    const int wg = tid >> 6, wl = tid & 63;
    const int arow = wl & 15, kgrp = wl >> 4;
    const int grow = wg * 512 + hs * 16 + arow;

    // B fragments resident in registers
    f16x8 wh[16], wi[9];
    #pragma unroll
    for (int kc = 0; kc < 16; ++kc)
        wh[kc] = *(const f16x8*)(whh + (size_t)grow * 512 + kc * 32 + kgrp * 8);
    #pragma unroll
    for (int kc = 0; kc < 9; ++kc)
        wi[kc] = *(const f16x8*)(wih + (size_t)grow * 288 + kc * 32 + kgrp * 8);
    const float bb = bias[grow];   // D col = lane&15 -> same index as B row

    // elementwise identity: thread owns (batch row irow, h col jcol)
    const int l = tid >> 2, r = tid & 3;
    const int jcol = l & 15, irow = ((l >> 4) << 2) + r;
    float c_st = 0.f;

    const int abase = btile * 16 + arow;
    unsigned* const mycnt = cnt + btile * 32;   // 128B-strided per-tile counters

    // x A-fragments for step t (single buffer; reloaded for t+1 after use)
    f16x8 xa[9];
    {
        const f16* q = newx + (size_t)abase * 288 + kgrp * 8;
        #pragma unroll
        for (int kc = 0; kc < 9; ++kc) xa[kc] = *(const f16x8*)(q + kc * 32);
    }

    for (int t = 0; t < TS; ++t) {
        f32x4 acc = {bb, bb, bb, bb};
        // x-projection part (independent of the barrier)
        #pragma unroll
        for (int kc = 0; kc < 9; ++kc)
            acc = __builtin_amdgcn_mfma_f32_16x16x32_f16(xa[kc], wi[kc], acc, 0, 0, 0);
        // reload xa for t+1 (completes during the spin)
        {
            const f16* q = newx + ((size_t)(t + 1) * 128 + abase) * 288 + kgrp * 8;
            #pragma unroll
            for (int kc = 0; kc < 9; ++kc) xa[kc] = *(const f16x8*)(q + kc * 32);
        }

        if (t > 0) {
            if (tid == 0) {
                const unsigned tgt = 32u * (unsigned)t;
                int spins = 0;
                while (__hip_atomic_load(mycnt, __ATOMIC_RELAXED,
                                         __HIP_MEMORY_SCOPE_AGENT) < tgt) {
                    __builtin_amdgcn_s_sleep(1);
                    if (++spins > (1 << 14)) break;   // degrade, never hang
                }
            }
            __syncthreads();
            // h(t-1) fragments straight from the LLC (sc0 sc1 = bypass L1+L2).
            // Loads + waitcnt in ONE asm block: consumers (MFMAs) have data deps
            // on outputs, so they cannot be scheduled before the internal wait.
            const f16* hp = hall + ((size_t)(t - 1) * 128 + abase) * 512 + kgrp * 8;
            f16x8 h00,h01,h02,h03,h04,h05,h06,h07,h08,h09,h10,h11,h12,h13,h14,h15;
            asm volatile(
                "global_load_dwordx4 %0,  %16, off sc0 sc1\n\t"
                "global_load_dwordx4 %1,  %16, off offset:64 sc0 sc1\n\t"
                "global_load_dwordx4 %2,  %16, off offset:128 sc0 sc1\n\t"
                "global_load_dwordx4 %3,  %16, off offset:192 sc0 sc1\n\t"
                "global_load_dwordx4 %4,  %16, off offset:256 sc0 sc1\n\t"
                "global_load_dwordx4 %5,  %16, off offset:320 sc0 sc1\n\t"
                "global_load_dwordx4 %6,  %16, off offset:384 sc0 sc1\n\t"
                "global_load_dwordx4 %7,  %16, off offset:448 sc0 sc1\n\t"
                "global_load_dwordx4 %8,  %16, off offset:512 sc0 sc1\n\t"
                "global_load_dwordx4 %9,  %16, off offset:576 sc0 sc1\n\t"
                "global_load_dwordx4 %10, %16, off offset:640 sc0 sc1\n\t"
                "global_load_dwordx4 %11, %16, off offset:704 sc0 sc1\n\t"
                "global_load_dwordx4 %12, %16, off offset:768 sc0 sc1\n\t"
                "global_load_dwordx4 %13, %16, off offset:832 sc0 sc1\n\t"
                "global_load_dwordx4 %14, %16, off offset:896 sc0 sc1\n\t"
                "global_load_dwordx4 %15, %16, off offset:960 sc0 sc1\n\t"
                "s_waitcnt vmcnt(0)"
                : "=&v"(h00), "=&v"(h01), "=&v"(h02), "=&v"(h03),
                  "=&v"(h04), "=&v"(h05), "=&v"(h06), "=&v"(h07),
                  "=&v"(h08), "=&v"(h09), "=&v"(h10), "=&v"(h11),
                  "=&v"(h12), "=&v"(h13), "=&v"(h14), "=&v"(h15)
                : "v"(hp)
                : "memory");
            acc = __builtin_amdgcn_mfma_f32_16x16x32_f16(h00, wh[0],  acc, 0, 0, 0);
            acc = __builtin_amdgcn_mfma_f32_16x16x32_f16(h01, wh[1],  acc, 0, 0, 0);
            acc = __builtin_amdgcn_mfma_f32_16x16x32_f16(h02, wh[2],  acc, 0, 0, 0);
            acc = __builtin_amdgcn_mfma_f32_16x16x32_f16(h03, wh[3],  acc, 0, 0, 0);
            acc = __builtin_amdgcn_mfma_f32_16x16x32_f16(h04, wh[4],  acc, 0, 0, 0);
            acc = __builtin_amdgcn_mfma_f32_16x16x32_f16(h05, wh[5],  acc, 0, 0, 0);
            acc = __builtin_amdgcn_mfma_f32_16x16x32_f16(h06, wh[6],  acc, 0, 0, 0);
            acc = __builtin_amdgcn_mfma_f32_16x16x32_f16(h07, wh[7],  acc, 0, 0, 0);
            acc = __builtin_amdgcn_mfma_f32_16x16x32_f16(h08, wh[8],  acc, 0, 0, 0);
            acc = __builtin_amdgcn_mfma_f32_16x16x32_f16(h09, wh[9],  acc, 0, 0, 0);
            acc = __builtin_amdgcn_mfma_f32_16x16x32_f16(h10, wh[10], acc, 0, 0, 0);
            acc = __builtin_amdgcn_mfma_f32_16x16x32_f16(h11, wh[11], acc, 0, 0, 0);
            acc = __builtin_amdgcn_mfma_f32_16x16x32_f16(h12, wh[12], acc, 0, 0, 0);
            acc = __builtin_amdgcn_mfma_f32_16x16x32_f16(h13, wh[13], acc, 0, 0, 0);
            acc = __builtin_amdgcn_mfma_f32_16x16x32_f16(h14, wh[14], acc, 0, 0, 0);
            acc = __builtin_amdgcn_mfma_f32_16x16x32_f16(h15, wh[15], acc, 0, 0, 0);
        }

        // gate exchange through LDS
        *(f32x4*)(gf + tid * 4) = acc;
        __syncthreads();
        float iv = sigm_dev(gf[tid]);
        float fv = sigm_dev(gf[256 + tid]);
        float gv = tanh_dev(gf[512 + tid]);
        float ov = sigm_dev(gf[768 + tid]);
        c_st = fv * c_st + iv * gv;
        float hv = ov * tanh_dev(c_st);

        // h store straight to LLC
        {
            f16 hv16 = (f16)hv;
            unsigned u32v = (unsigned)__builtin_bit_cast(unsigned short, hv16);
            const f16* sp = hall + ((size_t)t * 128 + btile * 16 + irow) * 512 + hs * 16 + jcol;
            asm volatile("global_store_short %0, %1, off sc0 sc1"
                         :: "v"(sp), "v"(u32v) : "memory");
        }
        // drain OUR asm stores (compiler's barrier waitcnt doesn't track asm ops),
        // also serves as the WAR barrier for gf reuse next step
        asm volatile("s_waitcnt vmcnt(0)" ::: "memory");
        __syncthreads();
        if (tid == 0)
            __hip_atomic_fetch_add(mycnt, 1u, __ATOMIC_RELAXED, __HIP_MEMORY_SCOPE_AGENT);
    }
}

// ---------------- phase 3: out = sigmoid(h_all @ W_fc^T + b_fc) ----------------
__global__ void __launch_bounds__(256) out_gemm(const f16* __restrict__ hall,
                                                const f16* __restrict__ wfc,
                                                const float* __restrict__ bfc,
                                                float* __restrict__ out) {
    const int tid = threadIdx.x;
    const int w = tid >> 6, wl = tid & 63;
    const int arow = wl & 15, kgrp = wl >> 4;
    const long m0 = (long)blockIdx.x * 64 + w * 16;
    const f16* ap = hall + (m0 + arow) * 512 + kgrp * 8;
    f16x8 a[16];
    #pragma unroll
    for (int kc = 0; kc < 16; ++kc) a[kc] = *(const f16x8*)(ap + kc * 32);
    #pragma unroll
    for (int jt = 0; jt < 8; ++jt) {
        f32x4 acc = {0.f, 0.f, 0.f, 0.f};
        const f16* bp = wfc + (size_t)(jt * 16 + arow) * 512 + kgrp * 8;
        #pragma unroll
        for (int kc = 0; kc < 16; ++kc)
            acc = __builtin_amdgcn_mfma_f32_16x16x32_f16(a[kc], *(const f16x8*)(bp + kc * 32),
                                                         acc, 0, 0, 0);
        const int col = jt * 16 + arow;        // D col = lane&15
        if (col < 123) {
            const float bv = bfc[col];
            #pragma unroll
            for (int rr = 0; rr < 4; ++rr) {
                long m = m0 + kgrp * 4 + rr;   // D row = (lane>>4)*4 + reg
                int tt = (int)(m >> 7), b = (int)(m & 127);
                out[((size_t)b * 499 + tt) * 123 + col] = sigm_dev(acc[rr] + bv);
            }
        }
    }
}

extern "C" void kernel_launch(void* const* d_in, const int* in_sizes, int n_in,
                              void* d_out, int out_size, void* d_ws, size_t ws_size,
                              hipStream_t stream) {
    if (ws_size < WS_NEED) return;   // safe no-op rather than OOB writes

    const float* x    = (const float*)d_in[0];
    const float* W_ih = (const float*)d_in[1];
    const float* W_hh = (const float*)d_in[2];
    const float* b_ih = (const float*)d_in[3];
    const float* b_hh = (const float*)d_in[4];
    const float* W_fc = (const float*)d_in[5];
    const float* b_fc = (const float*)d_in[6];
    float* out = (float*)d_out;
    char* ws = (char*)d_ws;

    f16* newx   = (f16*)(ws + NEWX_OFF);
    f16* hall   = (f16*)(ws + HALL_OFF);
    f16* whh    = (f16*)(ws + WHH_OFF);
    f16* wih    = (f16*)(ws + WIH_OFF);
    f16* wfc    = (f16*)(ws + WFC_OFF);
    float* bias = (float*)(ws + BIAS_OFF);
    unsigned* cnt = (unsigned*)(ws + CNT_OFF);

    // counters must be 0 at the start of every call (graph replays don't re-poison)
    hipMemsetAsync(cnt, 0, CNT_BYTES, stream);

    prep_newx<<<dim3(TS, 8), 256, 0, stream>>>(x, newx);
    prep_w<<<512, 256, 0, stream>>>(W_ih, W_hh, W_fc, b_ih, b_hh, whh, wih, wfc, bias);

    void* args[6] = {&newx, &hall, &whh, &wih, &bias, &cnt};
    hipLaunchCooperativeKernel((const void*)lstm_seq, dim3(256), dim3(256), args,
                               0, stream);

    out_gemm<<<998, 256, 0, stream>>>(hall, wfc, b_fc, out);
}

// Round 4
// 1867.013 us; speedup vs baseline: 2.4439x; 1.0359x over previous
//
#include <hip/hip_runtime.h>
#include <hip/hip_fp16.h>

// LSTM: B=128, T=500 (499 steps used), in=265 (padded 288), H=512, out=123.
// R4: per-tile runtime XCD-uniformity handshake. If a tile's 32 WGs share an
// XCD (expected under round-robin dispatch), h-exchange + barrier run through
// the per-XCD L2 (~90ns: sc0 loads, write-through stores, plain L2 atomics).
// Otherwise fall back to the R3 LLC path (sc0 sc1, sc1 atomics). Correctness
// never depends on placement (G16) -- only speed does.

typedef _Float16 f16;
typedef _Float16 f16x8 __attribute__((ext_vector_type(8)));
typedef float f32x4 __attribute__((ext_vector_type(4)));

#define TS 499

// ---- ws layout (bytes) ----
#define NEWX_OFF   0ul
#define NEWX_BYTES (500ul*128*288*2)
#define HALL_OFF   (NEWX_OFF + NEWX_BYTES)
#define HALL_BYTES (500ul*128*512*2)
#define WHH_OFF    (HALL_OFF + HALL_BYTES)
#define WHH_BYTES  (2048ul*512*2)
#define WIH_OFF    (WHH_OFF + WHH_BYTES)
#define WIH_BYTES  (2048ul*288*2)
#define WFC_OFF    (WIH_OFF + WIH_BYTES)
#define WFC_BYTES  (128ul*512*2)
#define BIAS_OFF   (WFC_OFF + WFC_BYTES)
#define BIAS_BYTES (2048ul*4)
#define CNT_OFF    (BIAS_OFF + BIAS_BYTES)
// cnt u32 indices: [0..255] step counters (tile b at b*32)
//                  [256..511] handshake counters (tile b at 256+b*32)
//                  [512..767] xcd publish slots (512 + b*32 + hs)
#define CNT_BYTES  (4096ul)
#define WS_NEED    (CNT_OFF + CNT_BYTES)

__device__ __forceinline__ float tanh_dev(float x) {
    float ax = fabsf(x);
    float e  = __expf(-2.f * ax);
    float r  = (1.f - e) / (1.f + e);
    return copysignf(r, x);
}
__device__ __forceinline__ float sigm_dev(float x) {
    float e = __expf(-fabsf(x));
    float p = 1.f / (1.f + e);
    return x >= 0.f ? p : 1.f - p;
}

// ---- coherence helpers ----
__device__ __forceinline__ void llc_store_u32(unsigned* p, unsigned v) {
    asm volatile("global_store_dword %0, %1, off sc0 sc1\n\ts_waitcnt vmcnt(0)"
                 :: "v"(p), "v"(v) : "memory");
}
__device__ __forceinline__ void llc_atomic_inc(unsigned* p) {
    unsigned one = 1u;
    asm volatile("global_atomic_add %0, %1, off sc1" :: "v"(p), "v"(one) : "memory");
}
__device__ __forceinline__ void l2_atomic_inc(unsigned* p) {
    unsigned one = 1u;
    asm volatile("global_atomic_add %0, %1, off" :: "v"(p), "v"(one) : "memory");
}
__device__ __forceinline__ unsigned llc_load_u32(const unsigned* p) {
    unsigned v;
    asm volatile("global_load_dword %0, %1, off sc0 sc1\n\ts_waitcnt vmcnt(0)"
                 : "=v"(v) : "v"(p) : "memory");
    return v;
}
__device__ __forceinline__ unsigned l2_load_u32(const unsigned* p) {
    unsigned v;
    asm volatile("global_load_dword %0, %1, off sc0\n\ts_waitcnt vmcnt(0)"
                 : "=v"(v) : "v"(p) : "memory");
    return v;
}

// ---------------- phase 1a: new_x = tanh(feats | onehot(diff) | onehot(ab)) ----------------
__global__ void __launch_bounds__(256) prep_newx(const float* __restrict__ x,
                                                 f16* __restrict__ newx) {
    const int t   = blockIdx.x;       // 0..498
    const int b0  = blockIdx.y * 16;
    const int tid = threadIdx.x;
    for (int bb = 0; bb < 16; ++bb) {
        const int b = b0 + bb;
        const float* xr = x + ((size_t)b * 500 + t) * 248;
        const int ab = (int)xr[246];
        const int df = (int)xr[247];
        f16* orow = newx + ((size_t)t * 128 + b) * 288;
        for (int k = tid; k < 288; k += 256) {
            float v;
            if (k < 246)      v = tanh_dev(xr[k]);
            else if (k < 257) v = (k - 246 == df) ? 0.76159415595576485f : 0.f;
            else if (k < 265) v = (k - 257 == ab) ? 0.76159415595576485f : 0.f;
            else              v = 0.f;
            orow[k] = (f16)v;
        }
    }
}

// ---------------- phase 1b: weights -> f16 (padded), bias combine ----------------
__global__ void __launch_bounds__(256) prep_w(const float* __restrict__ W_ih,
                                              const float* __restrict__ W_hh,
                                              const float* __restrict__ W_fc,
                                              const float* __restrict__ b_ih,
                                              const float* __restrict__ b_hh,
                                              f16* __restrict__ whh, f16* __restrict__ wih,
                                              f16* __restrict__ wfc, float* __restrict__ bias) {
    const int NHH = 2048 * 512;
    const int NIH = 2048 * 288;
    const int NFC = 128 * 512;
    const int NT  = NHH + NIH + NFC + 2048;
    for (int i = blockIdx.x * 256 + threadIdx.x; i < NT; i += gridDim.x * 256) {
        if (i < NHH) {
            whh[i] = (f16)W_hh[i];
        } else if (i < NHH + NIH) {
            int j2 = i - NHH; int rr = j2 / 288, kk = j2 % 288;
            wih[j2] = (kk < 265) ? (f16)W_ih[rr * 265 + kk] : (f16)0.f;
        } else if (i < NHH + NIH + NFC) {
            int j2 = i - (NHH + NIH); int rr = j2 >> 9, kk = j2 & 511;
            wfc[j2] = (rr < 123) ? (f16)W_fc[rr * 512 + kk] : (f16)0.f;
        } else {
            int j2 = i - (NHH + NIH + NFC);
            bias[j2] = b_ih[j2] + b_hh[j2];
        }
    }
}

// h-load asm: 16 x dwordx4 + internal vmcnt (consumers have data deps on outputs)
#define HLOAD_ASM(FLAGS)                                                      \
    asm volatile(                                                             \
        "global_load_dwordx4 %0,  %16, off " FLAGS "\n\t"                     \
        "global_load_dwordx4 %1,  %16, off offset:64 " FLAGS "\n\t"           \
        "global_load_dwordx4 %2,  %16, off offset:128 " FLAGS "\n\t"          \
        "global_load_dwordx4 %3,  %16, off offset:192 " FLAGS "\n\t"          \
        "global_load_dwordx4 %4,  %16, off offset:256 " FLAGS "\n\t"          \
        "global_load_dwordx4 %5,  %16, off offset:320 " FLAGS "\n\t"          \
        "global_load_dwordx4 %6,  %16, off offset:384 " FLAGS "\n\t"          \
        "global_load_dwordx4 %7,  %16, off offset:448 " FLAGS "\n\t"          \
        "global_load_dwordx4 %8,  %16, off offset:512 " FLAGS "\n\t"          \
        "global_load_dwordx4 %9,  %16, off offset:576 " FLAGS "\n\t"          \
        "global_load_dwordx4 %10, %16, off offset:640 " FLAGS "\n\t"          \
        "global_load_dwordx4 %11, %16, off offset:704 " FLAGS "\n\t"          \
        "global_load_dwordx4 %12, %16, off offset:768 " FLAGS "\n\t"          \
        "global_load_dwordx4 %13, %16, off offset:832 " FLAGS "\n\t"          \
        "global_load_dwordx4 %14, %16, off offset:896 " FLAGS "\n\t"          \
        "global_load_dwordx4 %15, %16, off offset:960 " FLAGS "\n\t"          \
        "s_waitcnt vmcnt(0)"                                                  \
        : "=&v"(h00), "=&v"(h01), "=&v"(h02), "=&v"(h03),                     \
          "=&v"(h04), "=&v"(h05), "=&v"(h06), "=&v"(h07),                     \
          "=&v"(h08), "=&v"(h09), "=&v"(h10), "=&v"(h11),                     \
          "=&v"(h12), "=&v"(h13), "=&v"(h14), "=&v"(h15)                      \
        : "v"(hp)                                                             \
        : "memory")

// ---------------- phase 2 main loop (templated on sync scope) ----------------
template <int UNI>
__device__ __forceinline__ void lstm_loop(const f16* __restrict__ newx,
                                          f16* __restrict__ hall,
                                          unsigned* mycnt,
                                          const f16x8 (&wh)[16], const f16x8 (&wi)[9],
                                          float bb, int btile, int hs, int tid,
                                          float* gf, volatile int* sflag) {
    const int wl = tid & 63;
    const int arow = wl & 15, kgrp = wl >> 4;
    const int l = tid >> 2, r = tid & 3;
    const int jcol = l & 15, irow = ((l >> 4) << 2) + r;
    const int abase = btile * 16 + arow;
    float c_st = 0.f;

    f16x8 xa[9];
    {
        const f16* q = newx + (size_t)abase * 288 + kgrp * 8;
        #pragma unroll
        for (int kc = 0; kc < 9; ++kc) xa[kc] = *(const f16x8*)(q + kc * 32);
    }

    for (int t = 0; t < TS; ++t) {
        f32x4 acc = {bb, bb, bb, bb};
        #pragma unroll
        for (int kc = 0; kc < 9; ++kc)
            acc = __builtin_amdgcn_mfma_f32_16x16x32_f16(xa[kc], wi[kc], acc, 0, 0, 0);
        // prefetch next step's x fragments (in flight during the spin)
        {
            const f16* q = newx + ((size_t)(t + 1) * 128 + abase) * 288 + kgrp * 8;
            #pragma unroll
            for (int kc = 0; kc < 9; ++kc) xa[kc] = *(const f16x8*)(q + kc * 32);
        }

        if (t > 0) {
            // wave0 polls the tile counter; LDS flag fans out to waves 1-3
            if (tid < 64) {
                const unsigned tgt = 32u * (unsigned)t;
                int spins = 0;
                for (;;) {
                    unsigned c = UNI ? l2_load_u32(mycnt) : llc_load_u32(mycnt);
                    if (c >= tgt) break;
                    __builtin_amdgcn_s_sleep(1);
                    if (++spins > (1 << 15)) break;   // degrade, never hang
                }
                if (tid == 0) *sflag = t;
            } else {
                int spins = 0;
                while (*sflag < t) {
                    __builtin_amdgcn_s_sleep(1);
                    if (++spins > (1 << 16)) break;
                }
            }
            const f16* hp = hall + ((size_t)(t - 1) * 128 + abase) * 512 + kgrp * 8;
            f16x8 h00,h01,h02,h03,h04,h05,h06,h07,h08,h09,h10,h11,h12,h13,h14,h15;
            if constexpr (UNI) HLOAD_ASM("sc0");
            else               HLOAD_ASM("sc0 sc1");
            // two independent MFMA chains halve dependent-MFMA latency
            f32x4 e0 = {0.f,0.f,0.f,0.f}, e1 = {0.f,0.f,0.f,0.f};
            e0 = __builtin_amdgcn_mfma_f32_16x16x32_f16(h00, wh[0],  e0, 0, 0, 0);
            e1 = __builtin_amdgcn_mfma_f32_16x16x32_f16(h01, wh[1],  e1, 0, 0, 0);
            e0 = __builtin_amdgcn_mfma_f32_16x16x32_f16(h02, wh[2],  e0, 0, 0, 0);
            e1 = __builtin_amdgcn_mfma_f32_16x16x32_f16(h03, wh[3],  e1, 0, 0, 0);
            e0 = __builtin_amdgcn_mfma_f32_16x16x32_f16(h04, wh[4],  e0, 0, 0, 0);
            e1 = __builtin_amdgcn_mfma_f32_16x16x32_f16(h05, wh[5],  e1, 0, 0, 0);
            e0 = __builtin_amdgcn_mfma_f32_16x16x32_f16(h06, wh[6],  e0, 0, 0, 0);
            e1 = __builtin_amdgcn_mfma_f32_16x16x32_f16(h07, wh[7],  e1, 0, 0, 0);
            e0 = __builtin_amdgcn_mfma_f32_16x16x32_f16(h08, wh[8],  e0, 0, 0, 0);
            e1 = __builtin_amdgcn_mfma_f32_16x16x32_f16(h09, wh[9],  e1, 0, 0, 0);
            e0 = __builtin_amdgcn_mfma_f32_16x16x32_f16(h10, wh[10], e0, 0, 0, 0);
            e1 = __builtin_amdgcn_mfma_f32_16x16x32_f16(h11, wh[11], e1, 0, 0, 0);
            e0 = __builtin_amdgcn_mfma_f32_16x16x32_f16(h12, wh[12], e0, 0, 0, 0);
            e1 = __builtin_amdgcn_mfma_f32_16x16x32_f16(h13, wh[13], e1, 0, 0, 0);
            e0 = __builtin_amdgcn_mfma_f32_16x16x32_f16(h14, wh[14], e0, 0, 0, 0);
            e1 = __builtin_amdgcn_mfma_f32_16x16x32_f16(h15, wh[15], e1, 0, 0, 0);
            acc += e0; acc += e1;
        }

        // gate exchange through LDS
        *(f32x4*)(gf + tid * 4) = acc;
        __syncthreads();
        float iv = sigm_dev(gf[tid]);
        float fv = sigm_dev(gf[256 + tid]);
        float gv = tanh_dev(gf[512 + tid]);
        float ov = sigm_dev(gf[768 + tid]);
        c_st = fv * c_st + iv * gv;
        float hv = ov * tanh_dev(c_st);

        {
            f16 hv16 = (f16)hv;
            unsigned u32v = (unsigned)__builtin_bit_cast(unsigned short, hv16);
            const f16* sp = hall + ((size_t)t * 128 + btile * 16 + irow) * 512 + hs * 16 + jcol;
            if constexpr (UNI)
                asm volatile("global_store_short %0, %1, off" :: "v"(sp), "v"(u32v) : "memory");
            else
                asm volatile("global_store_short %0, %1, off sc0 sc1" :: "v"(sp), "v"(u32v) : "memory");
        }
        asm volatile("s_waitcnt vmcnt(0)" ::: "memory");   // h acked at coherence point
        __syncthreads();                                    // all waves' stores done
        if (tid == 0) {
            if constexpr (UNI) l2_atomic_inc(mycnt);
            else               llc_atomic_inc(mycnt);
        }
    }
}

__global__ void __launch_bounds__(256, 1) lstm_seq(const f16* __restrict__ newx,
                                                   f16* __restrict__ hall,
                                                   const f16* __restrict__ whh,
                                                   const f16* __restrict__ wih,
                                                   const float* __restrict__ bias,
                                                   unsigned* __restrict__ cnt) {
    __shared__ float gf[1024];
    __shared__ int uni_sh;
    __shared__ volatile int sflag;
    const int tid   = threadIdx.x;
    const int btile = blockIdx.x & 7;
    const int hs    = blockIdx.x >> 3;

    const int wg = tid >> 6, wl = tid & 63;
    const int arow = wl & 15, kgrp = wl >> 4;
    const int grow = wg * 512 + hs * 16 + arow;

    f16x8 wh[16], wi[9];
    #pragma unroll
    for (int kc = 0; kc < 16; ++kc)
        wh[kc] = *(const f16x8*)(whh + (size_t)grow * 512 + kc * 32 + kgrp * 8);
    #pragma unroll
    for (int kc = 0; kc < 9; ++kc)
        wi[kc] = *(const f16x8*)(wih + (size_t)grow * 288 + kc * 32 + kgrp * 8);
    const float bb = bias[grow];

    unsigned xcd;
    asm volatile("s_getreg_b32 %0, hwreg(HW_REG_XCC_ID)" : "=s"(xcd));

    unsigned* mycnt = cnt + btile * 32;
    unsigned* hscnt = cnt + 256 + btile * 32;
    unsigned* slots = cnt + 512 + btile * 32;

    // --- placement handshake: is this tile entirely on one XCD? ---
    if (tid == 0) {
        llc_store_u32(&slots[hs], xcd);
        llc_atomic_inc(hscnt);
        sflag = 0;
    }
    if (tid < 64) {
        int spins = 0;
        while (llc_load_u32(hscnt) < 32u) {
            __builtin_amdgcn_s_sleep(8);
            if (++spins > (1 << 20)) break;
        }
        int ok = 1;
        if (tid < 32) ok = (llc_load_u32(&slots[tid]) == xcd) ? 1 : 0;
        unsigned long long m = __ballot(ok);
        if (tid == 0) uni_sh = (m == ~0ull) ? 1 : 0;
    }
    __syncthreads();

    if (uni_sh)
        lstm_loop<1>(newx, hall, mycnt, wh, wi, bb, btile, hs, tid, gf, &sflag);
    else
        lstm_loop<0>(newx, hall, mycnt, wh, wi, bb, btile, hs, tid, gf, &sflag);
}

// ---------------- phase 3: out = sigmoid(h_all @ W_fc^T + b_fc) ----------------
__global__ void __launch_bounds__(256) out_gemm(const f16* __restrict__ hall,
                                                const f16* __restrict__ wfc,
                                                const float* __restrict__ bfc,
                                                float* __restrict__ out) {
    const int tid = threadIdx.x;
    const int w = tid >> 6, wl = tid & 63;
    const int arow = wl & 15, kgrp = wl >> 4;
    const long m0 = (long)blockIdx.x * 64 + w * 16;
    const f16* ap = hall + (m0 + arow) * 512 + kgrp * 8;
    f16x8 a[16];
    #pragma unroll
    for (int kc = 0; kc < 16; ++kc) a[kc] = *(const f16x8*)(ap + kc * 32);
    #pragma unroll
    for (int jt = 0; jt < 8; ++jt) {
        f32x4 acc = {0.f, 0.f, 0.f, 0.f};
        const f16* bp = wfc + (size_t)(jt * 16 + arow) * 512 + kgrp * 8;
        #pragma unroll
        for (int kc = 0; kc < 16; ++kc)
            acc = __builtin_amdgcn_mfma_f32_16x16x32_f16(a[kc], *(const f16x8*)(bp + kc * 32),
                                                         acc, 0, 0, 0);
        const int col = jt * 16 + arow;        // D col = lane&15
        if (col < 123) {
            const float bv = bfc[col];
            #pragma unroll
            for (int rr = 0; rr < 4; ++rr) {
                long m = m0 + kgrp * 4 + rr;   // D row = (lane>>4)*4 + reg
                int tt = (int)(m >> 7), b = (int)(m & 127);
                out[((size_t)b * 499 + tt) * 123 + col] = sigm_dev(acc[rr] + bv);
            }
        }
    }
}

extern "C" void kernel_launch(void* const* d_in, const int* in_sizes, int n_in,
                              void* d_out, int out_size, void* d_ws, size_t ws_size,
                              hipStream_t stream) {
    if (ws_size < WS_NEED) return;   // safe no-op rather than OOB writes

    const float* x    = (const float*)d_in[0];
    const float* W_ih = (const float*)d_in[1];
    const float* W_hh = (const float*)d_in[2];
    const float* b_ih = (const float*)d_in[3];
    const float* b_hh = (const float*)d_in[4];
    const float* W_fc = (const float*)d_in[5];
    const float* b_fc = (const float*)d_in[6];
    float* out = (float*)d_out;
    char* ws = (char*)d_ws;

    f16* newx   = (f16*)(ws + NEWX_OFF);
    f16* hall   = (f16*)(ws + HALL_OFF);
    f16* whh    = (f16*)(ws + WHH_OFF);
    f16* wih    = (f16*)(ws + WIH_OFF);
    f16* wfc    = (f16*)(ws + WFC_OFF);
    float* bias = (float*)(ws + BIAS_OFF);
    unsigned* cnt = (unsigned*)(ws + CNT_OFF);

    // counters must be 0 at the start of every call (graph replays don't re-poison)
    hipMemsetAsync(cnt, 0, CNT_BYTES, stream);

    prep_newx<<<dim3(TS, 8), 256, 0, stream>>>(x, newx);
    prep_w<<<512, 256, 0, stream>>>(W_ih, W_hh, W_fc, b_ih, b_hh, whh, wih, wfc, bias);

    void* args[6] = {&newx, &hall, &whh, &wih, &bias, &cnt};
    hipLaunchCooperativeKernel((const void*)lstm_seq, dim3(256), dim3(256), args,
                               0, stream);

    out_gemm<<<998, 256, 0, stream>>>(hall, wfc, b_fc, out);
}